// Round 1
// baseline (1004.335 us; speedup 1.0000x reference)
//
#include <hip/hip_runtime.h>
#include <hip/hip_bf16.h>

typedef __hip_bfloat16 bf16;
typedef __attribute__((ext_vector_type(4))) float f32x4;
typedef __attribute__((ext_vector_type(8))) short short8;

#define NHEAD 16
#define NKV 4
#define HD 128
#define BATCH 4
#define SEQ 2048
#define DIMM 2048
#define NROWS (BATCH*SEQ)        // 8192
#define QKVN (DIMM + 2*NKV*HD)   // 3072

__device__ inline void gload_lds16(const bf16* g, bf16* l) {
  __builtin_amdgcn_global_load_lds(
      (const __attribute__((address_space(1))) unsigned int*)g,
      (__attribute__((address_space(3))) unsigned int*)l, 16, 0, 0);
}

// ---------------- fp32 -> bf16 conversion ----------------
__global__ void cvt_f32_bf16(const float* __restrict__ s, bf16* __restrict__ d, int n) {
  for (int i = (blockIdx.x * blockDim.x + threadIdx.x) * 4; i < n;
       i += gridDim.x * blockDim.x * 4) {
    const float4 v = *reinterpret_cast<const float4*>(s + i);
    alignas(8) bf16 t[4] = {__float2bfloat16(v.x), __float2bfloat16(v.y),
                            __float2bfloat16(v.z), __float2bfloat16(v.w)};
    *reinterpret_cast<uint2*>(d + i) = *reinterpret_cast<const uint2*>(t);
  }
}

// ---------------- GEMM: C[M][N] = A[M][K] * B[N][K]^T (bf16, fp32 accum) ----------------
__device__ inline void store_c(float* p, float v) { *p = v; }
__device__ inline void store_c(bf16* p, float v) { *p = __float2bfloat16(v); }

template <typename OutT>
__global__ __launch_bounds__(256) void gemm_bt(
    const bf16* __restrict__ A, const bf16* __restrict__ B0,
    const bf16* __restrict__ B1, OutT* __restrict__ C,
    int M, int N, int K, int Nsplit) {
  __shared__ __align__(16) bf16 As[128 * 64];
  __shared__ __align__(16) bf16 Bs[128 * 64];
  const int tid = threadIdx.x;
  const int w = tid >> 6, l = tid & 63;
  const int m0 = blockIdx.x * 128, n0 = blockIdx.y * 128;
  const bf16* Ap = A + (size_t)m0 * K;
  const bf16* Bp = (n0 < Nsplit) ? (B0 + (size_t)n0 * K)
                                 : (B1 + (size_t)(n0 - Nsplit) * K);
  const int wm = (w >> 1) * 64, wn = (w & 1) * 64;
  const int lr = l & 15, lk = (l >> 4) * 8;

  f32x4 acc[4][4] = {};

  for (int kt = 0; kt < K; kt += 64) {
#pragma unroll
    for (int i = 0; i < 4; ++i) {
      const int c = w * 64 + i * 256;   // wave-uniform chunk base
      const int cc = c + l;             // this lane's chunk
      const int row = cc >> 3, ci = cc & 7;
      gload_lds16(Ap + (size_t)row * K + kt + ci * 8, &As[c * 8]);
      gload_lds16(Bp + (size_t)row * K + kt + ci * 8, &Bs[c * 8]);
    }
    __syncthreads();
#pragma unroll
    for (int kk = 0; kk < 2; ++kk) {
      short8 a[4], b[4];
#pragma unroll
      for (int t = 0; t < 4; ++t) {
        a[t] = *(const short8*)&As[(wm + t * 16 + lr) * 64 + kk * 32 + lk];
        b[t] = *(const short8*)&Bs[(wn + t * 16 + lr) * 64 + kk * 32 + lk];
      }
#pragma unroll
      for (int mt = 0; mt < 4; ++mt)
#pragma unroll
        for (int nt = 0; nt < 4; ++nt)
          acc[mt][nt] = __builtin_amdgcn_mfma_f32_16x16x32_bf16(
              a[mt], b[nt], acc[mt][nt], 0, 0, 0);
    }
    __syncthreads();
  }

  const int cr = (l >> 4) * 4;
#pragma unroll
  for (int mt = 0; mt < 4; ++mt)
#pragma unroll
    for (int nt = 0; nt < 4; ++nt)
#pragma unroll
      for (int r = 0; r < 4; ++r) {
        const int row = m0 + wm + mt * 16 + cr + r;
        const int col = n0 + wn + nt * 16 + lr;
        store_c(&C[(size_t)row * N + col], acc[mt][nt][r]);
      }
}

// ---------------- RoPE (in-place on q heads + k heads of qkv buffer) ----------------
__global__ void rope_kernel(bf16* __restrict__ qkv) {
  const int idx = blockIdx.x * blockDim.x + threadIdx.x;
  const int total = NROWS * 20 * 64;  // 16 q heads + 4 k heads, 64 pairs each
  if (idx >= total) return;
  const int d = idx & 63;
  const int slot = (idx >> 6) % 20;
  const int row = idx / (64 * 20);
  const int col = (slot < 16) ? slot * 128 : DIMM + (slot - 16) * 128;
  const size_t base = (size_t)row * QKVN + col;
  const int pos = row & (SEQ - 1);
  // inv_freq = 10000^(-2d/128) = exp2(-(2d/128)*log2(10000))
  const float inv = exp2f((float)d * (-2.0f / 128.0f) * 13.287712379549449f);
  const float ang = (float)pos * inv;
  float sn, cs;
  __sincosf(ang, &sn, &cs);
  const float lo = __bfloat162float(qkv[base + d]);
  const float hi = __bfloat162float(qkv[base + d + 64]);
  qkv[base + d] = __float2bfloat16(lo * cs - hi * sn);
  qkv[base + d + 64] = __float2bfloat16(hi * cs + lo * sn);
}

// ---------------- Flash attention (causal, GQA) ----------------
// grid: (SEQ/64, BATCH*NHEAD); block 256 (4 waves, 16 q-rows per wave)
__global__ __launch_bounds__(256) void attn_kernel(
    const bf16* __restrict__ qkv, bf16* __restrict__ aout) {
  __shared__ __align__(16) bf16 Ks[32 * 128];
  __shared__ __align__(16) bf16 Vs[32 * 128];
  __shared__ __align__(16) bf16 Ps[4][16 * 32];
  const int tid = threadIdx.x, w = tid >> 6, l = tid & 63;
  const int qblk = blockIdx.x;
  const int bh = blockIdx.y;
  const int b = bh >> 4, h = bh & 15, kvh = h >> 2;
  const int lr = l & 15, lk = (l >> 4) * 8, cr = (l >> 4) * 4;

  // Q fragments (RoPE already applied); A-frag rows use lane&15
  const int q_s = qblk * 64 + w * 16 + lr;
  const bf16* qbase = qkv + (size_t)(b * SEQ + q_s) * QKVN + h * 128;
  short8 qf[4];
#pragma unroll
  for (int kk = 0; kk < 4; ++kk)
    qf[kk] = *(const short8*)(qbase + kk * 32 + lk);

  f32x4 o[8];
#pragma unroll
  for (int i = 0; i < 8; ++i) o[i] = f32x4{0.f, 0.f, 0.f, 0.f};
  float m[4], lsum[4];
#pragma unroll
  for (int r = 0; r < 4; ++r) { m[r] = -1e30f; lsum[r] = 0.f; }

  const float scale = 0.08838834764831845f;  // 1/sqrt(128)
  const int ntiles = 2 * qblk + 2;           // keys p <= qblk*64+63

  const bf16* Kg = qkv + (size_t)(b * SEQ) * QKVN + DIMM + kvh * 128;
  const bf16* Vg = Kg + NKV * 128;

  for (int kt = 0; kt < ntiles; ++kt) {
    // stage K,V tile [32][128]
#pragma unroll
    for (int i = 0; i < 2; ++i) {
      const int c = w * 64 + i * 256;
      const int cc = c + l;
      const int row = cc >> 4, ci = cc & 15;
      gload_lds16(Kg + (size_t)(kt * 32 + row) * QKVN + ci * 8, &Ks[c * 8]);
      gload_lds16(Vg + (size_t)(kt * 32 + row) * QKVN + ci * 8, &Vs[c * 8]);
    }
    __syncthreads();

    // S = Q K^T (two 16-col subtiles)
    f32x4 sacc[2];
#pragma unroll
    for (int nt = 0; nt < 2; ++nt) {
      sacc[nt] = f32x4{0.f, 0.f, 0.f, 0.f};
#pragma unroll
      for (int kk = 0; kk < 4; ++kk) {
        short8 bfrag = *(const short8*)&Ks[(nt * 16 + lr) * 128 + kk * 32 + lk];
        sacc[nt] = __builtin_amdgcn_mfma_f32_16x16x32_bf16(qf[kk], bfrag,
                                                           sacc[nt], 0, 0, 0);
      }
    }

    // online softmax per row
    float f[4];
#pragma unroll
    for (int r = 0; r < 4; ++r) {
      const int qrow = qblk * 64 + w * 16 + cr + r;
      float pv0 = sacc[0][r] * scale;
      float pv1 = sacc[1][r] * scale;
      if (kt * 32 + lr > qrow) pv0 = -1e30f;
      if (kt * 32 + 16 + lr > qrow) pv1 = -1e30f;
      float rmax = fmaxf(pv0, pv1);
#pragma unroll
      for (int off = 1; off < 16; off <<= 1)
        rmax = fmaxf(rmax, __shfl_xor(rmax, off, 16));
      const float mnew = fmaxf(m[r], rmax);
      f[r] = __expf(m[r] - mnew);
      m[r] = mnew;
      float e0 = __expf(pv0 - mnew);
      float e1 = __expf(pv1 - mnew);
      float rsum = e0 + e1;
#pragma unroll
      for (int off = 1; off < 16; off <<= 1) rsum += __shfl_xor(rsum, off, 16);
      lsum[r] = lsum[r] * f[r] + rsum;
      Ps[w][(cr + r) * 32 + lr] = __float2bfloat16(e0);
      Ps[w][(cr + r) * 32 + 16 + lr] = __float2bfloat16(e1);
    }
    // rescale O
#pragma unroll
    for (int dt = 0; dt < 8; ++dt)
#pragma unroll
      for (int r = 0; r < 4; ++r) o[dt][r] *= f[r];
    __syncthreads();

    // PV: A = P (16x32), B = V (32 x 16-chunk of d)
    const short8 pfrag = *(const short8*)&Ps[w][lr * 32 + lk];
    const short* Vss = (const short*)Vs;
#pragma unroll
    for (int dt = 0; dt < 8; ++dt) {
      short8 vfrag;
#pragma unroll
      for (int j = 0; j < 8; ++j)
        vfrag[j] = Vss[(lk + j) * 128 + dt * 16 + lr];
      o[dt] = __builtin_amdgcn_mfma_f32_16x16x32_bf16(pfrag, vfrag, o[dt], 0, 0, 0);
    }
    __syncthreads();
  }

  // normalize + write [b, s, h, d]
#pragma unroll
  for (int r = 0; r < 4; ++r) {
    const float inv = 1.0f / lsum[r];
    const int qrow = qblk * 64 + w * 16 + cr + r;
    bf16* outp = aout + (size_t)(b * SEQ + qrow) * DIMM + h * 128;
#pragma unroll
    for (int dt = 0; dt < 8; ++dt)
      outp[dt * 16 + lr] = __float2bfloat16(o[dt][r] * inv);
  }
}

// ---------------- launcher ----------------
extern "C" void kernel_launch(void* const* d_in, const int* in_sizes, int n_in,
                              void* d_out, int out_size, void* d_ws, size_t ws_size,
                              hipStream_t stream) {
  const float* x = (const float*)d_in[0];
  const float* Wq = (const float*)d_in[1];
  const float* Wkv = (const float*)d_in[2];
  const float* Wo = (const float*)d_in[3];
  float* out = (float*)d_out;

  bf16* xb = (bf16*)d_ws;                          // 8192*2048
  bf16* Wqb = xb + (size_t)NROWS * DIMM;           // 2048*2048
  bf16* Wkvb = Wqb + (size_t)DIMM * DIMM;          // 1024*2048
  bf16* Wob = Wkvb + (size_t)2 * NKV * HD * DIMM;  // 2048*2048
  bf16* attn = Wob + (size_t)DIMM * DIMM;          // 8192*2048
  bf16* qkv = (bf16*)d_out;  // 50.3MB scratch inside 67.1MB d_out; overwritten by final GEMM

  cvt_f32_bf16<<<2048, 256, 0, stream>>>(x, xb, NROWS * DIMM);
  cvt_f32_bf16<<<1024, 256, 0, stream>>>(Wq, Wqb, DIMM * DIMM);
  cvt_f32_bf16<<<512, 256, 0, stream>>>(Wkv, Wkvb, 2 * NKV * HD * DIMM);
  cvt_f32_bf16<<<1024, 256, 0, stream>>>(Wo, Wob, DIMM * DIMM);

  // fused QKV projection: N = 3072, cols [0,2048) from Wq, [2048,3072) from Wkv
  gemm_bt<bf16><<<dim3(NROWS / 128, QKVN / 128), 256, 0, stream>>>(
      xb, Wqb, Wkvb, qkv, NROWS, QKVN, DIMM, DIMM);

  rope_kernel<<<(NROWS * 20 * 64) / 256, 256, 0, stream>>>(qkv);

  attn_kernel<<<dim3(SEQ / 64, BATCH * NHEAD), 256, 0, stream>>>(qkv, attn);

  // output projection -> fp32 d_out
  gemm_bt<float><<<dim3(NROWS / 128, DIMM / 128), 256, 0, stream>>>(
      attn, Wob, Wob, out, NROWS, DIMM, DIMM, DIMM);
}

// Round 3
// 791.108 us; speedup vs baseline: 1.2695x; 1.2695x over previous
//
#include <hip/hip_runtime.h>
#include <hip/hip_bf16.h>

typedef __hip_bfloat16 bf16;
typedef __attribute__((ext_vector_type(4))) float f32x4;
typedef __attribute__((ext_vector_type(8))) short short8;

#define NHEAD 16
#define NKV 4
#define HD 128
#define BATCH 4
#define SEQ 2048
#define DIMM 2048
#define NROWS (BATCH*SEQ)        // 8192
#define QKVN (DIMM + 2*NKV*HD)   // 3072

__device__ inline void gload_lds16(const bf16* g, bf16* l) {
  __builtin_amdgcn_global_load_lds(
      (const __attribute__((address_space(1))) unsigned int*)g,
      (__attribute__((address_space(3))) unsigned int*)l, 16, 0, 0);
}

__device__ inline short bf16bits(float f) {
  bf16 h = __float2bfloat16(f);
  return *reinterpret_cast<short*>(&h);
}

// ---------------- fp32 -> bf16 conversion ----------------
__global__ void cvt_f32_bf16(const float* __restrict__ s, bf16* __restrict__ d, int n) {
  for (int i = (blockIdx.x * blockDim.x + threadIdx.x) * 4; i < n;
       i += gridDim.x * blockDim.x * 4) {
    const float4 v = *reinterpret_cast<const float4*>(s + i);
    alignas(8) bf16 t[4] = {__float2bfloat16(v.x), __float2bfloat16(v.y),
                            __float2bfloat16(v.z), __float2bfloat16(v.w)};
    *reinterpret_cast<uint2*>(d + i) = *reinterpret_cast<const uint2*>(t);
  }
}

// ---------------- GEMM: C[M][N] = A[M][K] * B[N][K]^T (bf16, fp32 accum) ----------------
__device__ inline void store_c(float* p, float v) { *p = v; }
__device__ inline void store_c(bf16* p, float v) { *p = __float2bfloat16(v); }

template <typename OutT>
__global__ __launch_bounds__(256) void gemm_bt(
    const bf16* __restrict__ A, const bf16* __restrict__ B0,
    const bf16* __restrict__ B1, OutT* __restrict__ C,
    int M, int N, int K, int Nsplit) {
  __shared__ __align__(16) bf16 As[128 * 64];
  __shared__ __align__(16) bf16 Bs[128 * 64];
  const int tid = threadIdx.x;
  const int w = tid >> 6, l = tid & 63;
  const int m0 = blockIdx.x * 128, n0 = blockIdx.y * 128;
  const bf16* Ap = A + (size_t)m0 * K;
  const bf16* Bp = (n0 < Nsplit) ? (B0 + (size_t)n0 * K)
                                 : (B1 + (size_t)(n0 - Nsplit) * K);
  const int wm = (w >> 1) * 64, wn = (w & 1) * 64;
  const int lr = l & 15, lk = (l >> 4) * 8;

  f32x4 acc[4][4] = {};

  for (int kt = 0; kt < K; kt += 64) {
#pragma unroll
    for (int i = 0; i < 4; ++i) {
      const int c = w * 64 + i * 256;   // wave-uniform chunk base
      const int cc = c + l;             // this lane's chunk
      const int row = cc >> 3, ci = cc & 7;
      gload_lds16(Ap + (size_t)row * K + kt + ci * 8, &As[c * 8]);
      gload_lds16(Bp + (size_t)row * K + kt + ci * 8, &Bs[c * 8]);
    }
    __syncthreads();
#pragma unroll
    for (int kk = 0; kk < 2; ++kk) {
      short8 a[4], b[4];
#pragma unroll
      for (int t = 0; t < 4; ++t) {
        a[t] = *(const short8*)&As[(wm + t * 16 + lr) * 64 + kk * 32 + lk];
        b[t] = *(const short8*)&Bs[(wn + t * 16 + lr) * 64 + kk * 32 + lk];
      }
#pragma unroll
      for (int mt = 0; mt < 4; ++mt)
#pragma unroll
        for (int nt = 0; nt < 4; ++nt)
          acc[mt][nt] = __builtin_amdgcn_mfma_f32_16x16x32_bf16(
              a[mt], b[nt], acc[mt][nt], 0, 0, 0);
    }
    __syncthreads();
  }

  const int cr = (l >> 4) * 4;
#pragma unroll
  for (int mt = 0; mt < 4; ++mt)
#pragma unroll
    for (int nt = 0; nt < 4; ++nt)
#pragma unroll
      for (int r = 0; r < 4; ++r) {
        const int row = m0 + wm + mt * 16 + cr + r;
        const int col = n0 + wn + nt * 16 + lr;
        store_c(&C[(size_t)row * N + col], acc[mt][nt][r]);
      }
}

// ---------------- RoPE (in-place on q heads + k heads of qkv buffer) ----------------
__global__ void rope_kernel(bf16* __restrict__ qkv) {
  const int idx = blockIdx.x * blockDim.x + threadIdx.x;
  const int total = NROWS * 20 * 64;  // 16 q heads + 4 k heads, 64 pairs each
  if (idx >= total) return;
  const int d = idx & 63;
  const int slot = (idx >> 6) % 20;
  const int row = idx / (64 * 20);
  const int col = (slot < 16) ? slot * 128 : DIMM + (slot - 16) * 128;
  const size_t base = (size_t)row * QKVN + col;
  const int pos = row & (SEQ - 1);
  const float inv = exp2f((float)d * (-2.0f / 128.0f) * 13.287712379549449f);
  const float ang = (float)pos * inv;
  float sn, cs;
  __sincosf(ang, &sn, &cs);
  const float lo = __bfloat162float(qkv[base + d]);
  const float hi = __bfloat162float(qkv[base + d + 64]);
  qkv[base + d] = __float2bfloat16(lo * cs - hi * sn);
  qkv[base + d + 64] = __float2bfloat16(hi * cs + lo * sn);
}

// ---------------- Flash attention (causal, GQA) ----------------
// grid: (SEQ/64, BATCH*NHEAD); block 256 (4 waves, 16 q-rows per wave)
// K tile: [32][128] in LDS, chunk-XOR-swizzled (chunk ci holds global chunk ci^(row&7))
// V tile: stored TRANSPOSED Vt[d][kv], row stride 40 elems (80B) -> b128 PV reads
__global__ __launch_bounds__(256) void attn_kernel(
    const bf16* __restrict__ qkv, bf16* __restrict__ aout) {
  __shared__ __align__(16) short Ks[32 * 128];
  __shared__ __align__(16) short Vts[128 * 40];
  __shared__ __align__(16) short Ps[4][16 * 40];
  const int tid = threadIdx.x, w = tid >> 6, l = tid & 63;
  const int qblk = (SEQ / 64 - 1) - blockIdx.x;  // longest blocks first
  const int bh = blockIdx.y;
  const int b = bh >> 4, h = bh & 15, kvh = h >> 2;
  const int lr = l & 15, lk8 = l >> 4, lk = lk8 * 8, cr = lk8 * 4;

  // Q fragments (RoPE already applied)
  const int q_s = qblk * 64 + w * 16 + lr;
  const bf16* qbase = qkv + (size_t)(b * SEQ + q_s) * QKVN + h * 128;
  short8 qf[4];
#pragma unroll
  for (int kk = 0; kk < 4; ++kk)
    qf[kk] = *(const short8*)(qbase + kk * 32 + lk);

  f32x4 o[8];
#pragma unroll
  for (int i = 0; i < 8; ++i) o[i] = f32x4{0.f, 0.f, 0.f, 0.f};
  float m[4], lsum[4];
#pragma unroll
  for (int r = 0; r < 4; ++r) { m[r] = -1e30f; lsum[r] = 0.f; }

  const float scale = 0.08838834764831845f;  // 1/sqrt(128)
  const int ntiles = 2 * qblk + 2;

  const bf16* Kg = qkv + (size_t)(b * SEQ) * QKVN + DIMM + kvh * 128;
  const bf16* Vg = Kg + NKV * 128;

  for (int kt = 0; kt < ntiles; ++kt) {
    // --- stage K [32][128] via global_load_lds, source pre-swizzled ---
#pragma unroll
    for (int i = 0; i < 2; ++i) {
      const int c = (i * 4 + w) * 64;
      const int cc = c + l;
      const int row = cc >> 4, ci = cc & 15;
      const int sc = ci ^ (row & 7);
      gload_lds16(Kg + (size_t)(kt * 32 + row) * QKVN + sc * 8, (bf16*)&Ks[c * 8]);
    }
    // --- stage V transposed: reg-stage, 32 kv x 2 adjacent d-chunks per wave ---
    short8 vst[2];
#pragma unroll
    for (int i2 = 0; i2 < 2; ++i2) {
      const int kv = l >> 1;
      const int dc = (i2 * 4 + w) * 2 + (l & 1);
      vst[i2] = *(const short8*)(Vg + (size_t)(kt * 32 + kv) * QKVN + dc * 8);
    }
#pragma unroll
    for (int i2 = 0; i2 < 2; ++i2) {
      const int kv = l >> 1;
      const int d0 = ((i2 * 4 + w) * 2 + (l & 1)) * 8;
#pragma unroll
      for (int i = 0; i < 8; ++i) Vts[(d0 + i) * 40 + kv] = vst[i2][i];
    }
    __syncthreads();

    // --- S = Q K^T (swizzled K reads) ---
    f32x4 sacc[2];
#pragma unroll
    for (int nt = 0; nt < 2; ++nt) {
      sacc[nt] = f32x4{0.f, 0.f, 0.f, 0.f};
      const int row = nt * 16 + lr;
      const int rsw = row & 7;
#pragma unroll
      for (int kk = 0; kk < 4; ++kk) {
        const short8 bfrag =
            *(const short8*)&Ks[row * 128 + (((kk << 2) + lk8) ^ rsw) * 8];
        sacc[nt] = __builtin_amdgcn_mfma_f32_16x16x32_bf16(qf[kk], bfrag,
                                                           sacc[nt], 0, 0, 0);
      }
    }

    // --- online softmax per row ---
    const bool needmask = (kt >= 2 * qblk);
    float f[4];
#pragma unroll
    for (int r = 0; r < 4; ++r) {
      const int qrow = qblk * 64 + w * 16 + cr + r;
      float pv0 = sacc[0][r] * scale;
      float pv1 = sacc[1][r] * scale;
      if (needmask) {
        if (kt * 32 + lr > qrow) pv0 = -1e30f;
        if (kt * 32 + 16 + lr > qrow) pv1 = -1e30f;
      }
      float rmax = fmaxf(pv0, pv1);
#pragma unroll
      for (int off = 1; off < 16; off <<= 1)
        rmax = fmaxf(rmax, __shfl_xor(rmax, off, 16));
      const float mnew = fmaxf(m[r], rmax);
      f[r] = __expf(m[r] - mnew);
      m[r] = mnew;
      float e0 = __expf(pv0 - mnew);
      float e1 = __expf(pv1 - mnew);
      float rsum = e0 + e1;
#pragma unroll
      for (int off = 1; off < 16; off <<= 1) rsum += __shfl_xor(rsum, off, 16);
      lsum[r] = lsum[r] * f[r] + rsum;
      Ps[w][(cr + r) * 40 + lr] = bf16bits(e0);
      Ps[w][(cr + r) * 40 + 16 + lr] = bf16bits(e1);
    }
#pragma unroll
    for (int dt = 0; dt < 8; ++dt)
#pragma unroll
      for (int r = 0; r < 4; ++r) o[dt][r] *= f[r];

    // --- PV (same-wave P write->read: DS in-order, no barrier needed) ---
    const short8 pfrag = *(const short8*)&Ps[w][lr * 40 + lk];
#pragma unroll
    for (int dt = 0; dt < 8; ++dt) {
      const short8 vfrag = *(const short8*)&Vts[(dt * 16 + lr) * 40 + lk];
      o[dt] = __builtin_amdgcn_mfma_f32_16x16x32_bf16(pfrag, vfrag, o[dt], 0, 0, 0);
    }
    __syncthreads();
  }

  // normalize + write [b, s, h, d]
#pragma unroll
  for (int r = 0; r < 4; ++r) {
    const float inv = 1.0f / lsum[r];
    const int qrow = qblk * 64 + w * 16 + cr + r;
    bf16* outp = aout + (size_t)(b * SEQ + qrow) * DIMM + h * 128;
#pragma unroll
    for (int dt = 0; dt < 8; ++dt)
      outp[dt * 16 + lr] = __float2bfloat16(o[dt][r] * inv);
  }
}

// ---------------- launcher ----------------
extern "C" void kernel_launch(void* const* d_in, const int* in_sizes, int n_in,
                              void* d_out, int out_size, void* d_ws, size_t ws_size,
                              hipStream_t stream) {
  const float* x = (const float*)d_in[0];
  const float* Wq = (const float*)d_in[1];
  const float* Wkv = (const float*)d_in[2];
  const float* Wo = (const float*)d_in[3];
  float* out = (float*)d_out;

  bf16* xb = (bf16*)d_ws;                          // 8192*2048
  bf16* Wqb = xb + (size_t)NROWS * DIMM;           // 2048*2048
  bf16* Wkvb = Wqb + (size_t)DIMM * DIMM;          // 1024*2048
  bf16* Wob = Wkvb + (size_t)2 * NKV * HD * DIMM;  // 2048*2048
  bf16* attn = Wob + (size_t)DIMM * DIMM;          // 8192*2048
  bf16* qkv = (bf16*)d_out;  // 50.3MB scratch inside 67.1MB d_out

  cvt_f32_bf16<<<2048, 256, 0, stream>>>(x, xb, NROWS * DIMM);
  cvt_f32_bf16<<<1024, 256, 0, stream>>>(Wq, Wqb, DIMM * DIMM);
  cvt_f32_bf16<<<512, 256, 0, stream>>>(Wkv, Wkvb, 2 * NKV * HD * DIMM);
  cvt_f32_bf16<<<1024, 256, 0, stream>>>(Wo, Wob, DIMM * DIMM);

  gemm_bt<bf16><<<dim3(NROWS / 128, QKVN / 128), 256, 0, stream>>>(
      xb, Wqb, Wkvb, qkv, NROWS, QKVN, DIMM, DIMM);

  rope_kernel<<<(NROWS * 20 * 64) / 256, 256, 0, stream>>>(qkv);

  attn_kernel<<<dim3(SEQ / 64, BATCH * NHEAD), 256, 0, stream>>>(qkv, attn);

  gemm_bt<float><<<dim3(NROWS / 128, DIMM / 128), 256, 0, stream>>>(
      attn, Wob, Wob, out, NROWS, DIMM, DIMM, DIMM);
}

// Round 4
// 677.186 us; speedup vs baseline: 1.4831x; 1.1682x over previous
//
#include <hip/hip_runtime.h>
#include <hip/hip_bf16.h>

typedef __hip_bfloat16 bf16;
typedef __attribute__((ext_vector_type(4))) float f32x4;
typedef __attribute__((ext_vector_type(8))) short short8;

#define NHEAD 16
#define NKV 4
#define HD 128
#define BATCH 4
#define SEQ 2048
#define DIMM 2048
#define NROWS (BATCH*SEQ)        // 8192
#define QKVN (DIMM + 2*NKV*HD)   // 3072

#define WAIT_VMCNT0 asm volatile("s_waitcnt vmcnt(0)" ::: "memory")
#define WAIT_LGKM0  asm volatile("s_waitcnt lgkmcnt(0)" ::: "memory")

__device__ inline void gload_lds16(const bf16* g, bf16* l) {
  __builtin_amdgcn_global_load_lds(
      (const __attribute__((address_space(1))) unsigned int*)g,
      (__attribute__((address_space(3))) unsigned int*)l, 16, 0, 0);
}

__device__ inline short bf16bits(float f) {
  bf16 h = __float2bfloat16(f);
  return *reinterpret_cast<short*>(&h);
}

// ---------------- fp32 -> bf16 conversion ----------------
__global__ void cvt_f32_bf16(const float* __restrict__ s, bf16* __restrict__ d, int n) {
  for (int i = (blockIdx.x * blockDim.x + threadIdx.x) * 4; i < n;
       i += gridDim.x * blockDim.x * 4) {
    const float4 v = *reinterpret_cast<const float4*>(s + i);
    alignas(8) bf16 t[4] = {__float2bfloat16(v.x), __float2bfloat16(v.y),
                            __float2bfloat16(v.z), __float2bfloat16(v.w)};
    *reinterpret_cast<uint2*>(d + i) = *reinterpret_cast<const uint2*>(t);
  }
}

// ---------------- GEMM: C[M][N] = A[M][K] * B[N][K]^T (bf16, fp32 accum) ----------------
__device__ inline void store_c(float* p, float v) { *p = v; }
__device__ inline void store_c(bf16* p, float v) { *p = __float2bfloat16(v); }

template <typename OutT>
__global__ __launch_bounds__(256) void gemm_bt(
    const bf16* __restrict__ A, const bf16* __restrict__ B0,
    const bf16* __restrict__ B1, OutT* __restrict__ C,
    int M, int N, int K, int Nsplit) {
  __shared__ __align__(16) bf16 As[128 * 64];
  __shared__ __align__(16) bf16 Bs[128 * 64];
  const int tid = threadIdx.x;
  const int w = tid >> 6, l = tid & 63;
  const int m0 = blockIdx.x * 128, n0 = blockIdx.y * 128;
  const bf16* Ap = A + (size_t)m0 * K;
  const bf16* Bp = (n0 < Nsplit) ? (B0 + (size_t)n0 * K)
                                 : (B1 + (size_t)(n0 - Nsplit) * K);
  const int wm = (w >> 1) * 64, wn = (w & 1) * 64;
  const int lr = l & 15, lk = (l >> 4) * 8;

  f32x4 acc[4][4] = {};

  for (int kt = 0; kt < K; kt += 64) {
#pragma unroll
    for (int i = 0; i < 4; ++i) {
      const int c = w * 64 + i * 256;   // wave-uniform chunk base
      const int cc = c + l;             // this lane's chunk
      const int row = cc >> 3, ci = cc & 7;
      gload_lds16(Ap + (size_t)row * K + kt + ci * 8, &As[c * 8]);
      gload_lds16(Bp + (size_t)row * K + kt + ci * 8, &Bs[c * 8]);
    }
    __syncthreads();
#pragma unroll
    for (int kk = 0; kk < 2; ++kk) {
      short8 a[4], b[4];
#pragma unroll
      for (int t = 0; t < 4; ++t) {
        a[t] = *(const short8*)&As[(wm + t * 16 + lr) * 64 + kk * 32 + lk];
        b[t] = *(const short8*)&Bs[(wn + t * 16 + lr) * 64 + kk * 32 + lk];
      }
#pragma unroll
      for (int mt = 0; mt < 4; ++mt)
#pragma unroll
        for (int nt = 0; nt < 4; ++nt)
          acc[mt][nt] = __builtin_amdgcn_mfma_f32_16x16x32_bf16(
              a[mt], b[nt], acc[mt][nt], 0, 0, 0);
    }
    __syncthreads();
  }

  const int cr = (l >> 4) * 4;
#pragma unroll
  for (int mt = 0; mt < 4; ++mt)
#pragma unroll
    for (int nt = 0; nt < 4; ++nt)
#pragma unroll
      for (int r = 0; r < 4; ++r) {
        const int row = m0 + wm + mt * 16 + cr + r;
        const int col = n0 + wn + nt * 16 + lr;
        store_c(&C[(size_t)row * N + col], acc[mt][nt][r]);
      }
}

// ---------------- RoPE (in-place on q heads + k heads of qkv buffer) ----------------
__global__ void rope_kernel(bf16* __restrict__ qkv) {
  const int idx = blockIdx.x * blockDim.x + threadIdx.x;
  const int total = NROWS * 20 * 64;  // 16 q heads + 4 k heads, 64 pairs each
  if (idx >= total) return;
  const int d = idx & 63;
  const int slot = (idx >> 6) % 20;
  const int row = idx / (64 * 20);
  const int col = (slot < 16) ? slot * 128 : DIMM + (slot - 16) * 128;
  const size_t base = (size_t)row * QKVN + col;
  const int pos = row & (SEQ - 1);
  const float inv = exp2f((float)d * (-2.0f / 128.0f) * 13.287712379549449f);
  const float ang = (float)pos * inv;
  float sn, cs;
  __sincosf(ang, &sn, &cs);
  const float lo = __bfloat162float(qkv[base + d]);
  const float hi = __bfloat162float(qkv[base + d + 64]);
  qkv[base + d] = __float2bfloat16(lo * cs - hi * sn);
  qkv[base + d + 64] = __float2bfloat16(hi * cs + lo * sn);
}

// ---------------- Flash attention (causal, GQA) ----------------
// grid: (SEQ/64, BATCH*NHEAD); block 256 (4 waves, 16 q-rows per wave)
// Pipelined: K double-buffered in LDS (gload_lds, XOR-swizzled source),
// V reg-staged one tile ahead then scattered transposed into Vts.
// Raw s_barrier + manual waitcnt (no __syncthreads vmcnt(0) drain).
__global__ __launch_bounds__(256) void attn_kernel(
    const bf16* __restrict__ qkv, bf16* __restrict__ aout) {
  __shared__ __align__(16) short Ks[2][32 * 128];
  __shared__ __align__(16) short Vts[128 * 40];
  __shared__ __align__(16) short Ps[4][16 * 40];
  const int tid = threadIdx.x, w = tid >> 6, l = tid & 63;
  const int qblk = (SEQ / 64 - 1) - blockIdx.x;  // longest blocks first
  const int bh = blockIdx.y;
  const int b = bh >> 4, h = bh & 15, kvh = h >> 2;
  const int lr = l & 15, lk8 = l >> 4, lk = lk8 * 8, cr = lk8 * 4;

  // Q fragments (RoPE already applied)
  const int q_s = qblk * 64 + w * 16 + lr;
  const bf16* qbase = qkv + (size_t)(b * SEQ + q_s) * QKVN + h * 128;
  short8 qf[4];
#pragma unroll
  for (int kk = 0; kk < 4; ++kk)
    qf[kk] = *(const short8*)(qbase + kk * 32 + lk);

  f32x4 o[8];
#pragma unroll
  for (int i = 0; i < 8; ++i) o[i] = f32x4{0.f, 0.f, 0.f, 0.f};
  float m[4], lsum[4];
#pragma unroll
  for (int r = 0; r < 4; ++r) { m[r] = -1e30f; lsum[r] = 0.f; }

  const float scale = 0.08838834764831845f;  // 1/sqrt(128)
  const int ntiles = 2 * qblk + 2;

  const bf16* Kg = qkv + (size_t)(b * SEQ) * QKVN + DIMM + kvh * 128;
  const bf16* Vg = Kg + NKV * 128;

  auto issueK = [&](int kt, int buf) {
#pragma unroll
    for (int i = 0; i < 2; ++i) {
      const int c = (i * 4 + w) * 64;
      const int cc = c + l;
      const int row = cc >> 4, ci = cc & 15;
      const int sc = ci ^ (row & 7);
      gload_lds16(Kg + (size_t)(kt * 32 + row) * QKVN + sc * 8,
                  (bf16*)&Ks[buf][c * 8]);
    }
  };
  auto loadV = [&](int kt, short8* v) {
#pragma unroll
    for (int i2 = 0; i2 < 2; ++i2) {
      const int kv = l >> 1;
      const int dc = (i2 * 4 + w) * 2 + (l & 1);
      v[i2] = *(const short8*)(Vg + (size_t)(kt * 32 + kv) * QKVN + dc * 8);
    }
  };

  // prologue: stage tile 0
  short8 vst[2], vst2[2];
  issueK(0, 0);
  loadV(0, vst);
  WAIT_VMCNT0;
  __builtin_amdgcn_s_barrier();
  __builtin_amdgcn_sched_barrier(0);

  for (int kt = 0; kt < ntiles; ++kt) {
    const int cur = kt & 1;
    // --- write V[kt] regs -> transposed LDS ---
#pragma unroll
    for (int i2 = 0; i2 < 2; ++i2) {
      const int kv = l >> 1;
      const int d0 = ((i2 * 4 + w) * 2 + (l & 1)) * 8;
#pragma unroll
      for (int i = 0; i < 8; ++i) Vts[(d0 + i) * 40 + kv] = vst[i2][i];
    }
    // --- prefetch tile kt+1 ---
    if (kt + 1 < ntiles) {
      issueK(kt + 1, cur ^ 1);
      loadV(kt + 1, vst2);
    }

    // --- S = Q K^T from Ks[cur] (swizzled reads) ---
    f32x4 sacc[2];
#pragma unroll
    for (int nt = 0; nt < 2; ++nt) {
      sacc[nt] = f32x4{0.f, 0.f, 0.f, 0.f};
      const int row = nt * 16 + lr;
      const int rsw = row & 7;
#pragma unroll
      for (int kk = 0; kk < 4; ++kk) {
        const short8 bfrag =
            *(const short8*)&Ks[cur][row * 128 + (((kk << 2) + lk8) ^ rsw) * 8];
        sacc[nt] = __builtin_amdgcn_mfma_f32_16x16x32_bf16(qf[kk], bfrag,
                                                           sacc[nt], 0, 0, 0);
      }
    }

    // --- online softmax per row (lsum kept as per-lane partials) ---
    const bool needmask = (kt >= 2 * qblk);
    float f[4];
#pragma unroll
    for (int r = 0; r < 4; ++r) {
      const int qrow = qblk * 64 + w * 16 + cr + r;
      float pv0 = sacc[0][r] * scale;
      float pv1 = sacc[1][r] * scale;
      if (needmask) {
        if (kt * 32 + lr > qrow) pv0 = -1e30f;
        if (kt * 32 + 16 + lr > qrow) pv1 = -1e30f;
      }
      float rmax = fmaxf(pv0, pv1);
#pragma unroll
      for (int off = 1; off < 16; off <<= 1)
        rmax = fmaxf(rmax, __shfl_xor(rmax, off, 16));
      const float mnew = fmaxf(m[r], rmax);
      f[r] = __expf(m[r] - mnew);
      m[r] = mnew;
      const float e0 = __expf(pv0 - mnew);
      const float e1 = __expf(pv1 - mnew);
      lsum[r] = lsum[r] * f[r] + (e0 + e1);
      Ps[w][(cr + r) * 40 + lr] = bf16bits(e0);
      Ps[w][(cr + r) * 40 + 16 + lr] = bf16bits(e1);
    }
    // skip O-rescale when no row's max moved (common after early tiles)
    if (!__all(f[0] == 1.f && f[1] == 1.f && f[2] == 1.f && f[3] == 1.f)) {
#pragma unroll
      for (int dt = 0; dt < 8; ++dt)
#pragma unroll
        for (int r = 0; r < 4; ++r) o[dt][r] *= f[r];
    }

    WAIT_LGKM0;                       // own Vts/Ps writes drained
    __builtin_amdgcn_s_barrier();     // all waves' Vts writes visible
    __builtin_amdgcn_sched_barrier(0);

    // --- PV ---
    const short8 pfrag = *(const short8*)&Ps[w][lr * 40 + lk];
#pragma unroll
    for (int dt = 0; dt < 8; ++dt) {
      const short8 vfrag = *(const short8*)&Vts[(dt * 16 + lr) * 40 + lk];
      o[dt] = __builtin_amdgcn_mfma_f32_16x16x32_bf16(pfrag, vfrag, o[dt], 0, 0, 0);
    }

    WAIT_VMCNT0;                      // K[kt+1] in LDS, V[kt+1] in regs
    __builtin_amdgcn_s_barrier();     // all waves done reading Vts
    __builtin_amdgcn_sched_barrier(0);
    vst[0] = vst2[0];
    vst[1] = vst2[1];
  }

  // final lsum reduction across the 16-lane group
#pragma unroll
  for (int r = 0; r < 4; ++r) {
    float s = lsum[r];
#pragma unroll
    for (int off = 1; off < 16; off <<= 1) s += __shfl_xor(s, off, 16);
    lsum[r] = s;
  }

  // normalize + write [b, s, h, d]
#pragma unroll
  for (int r = 0; r < 4; ++r) {
    const float inv = 1.0f / lsum[r];
    const int qrow = qblk * 64 + w * 16 + cr + r;
    bf16* outp = aout + (size_t)(b * SEQ + qrow) * DIMM + h * 128;
#pragma unroll
    for (int dt = 0; dt < 8; ++dt)
      outp[dt * 16 + lr] = __float2bfloat16(o[dt][r] * inv);
  }
}

// ---------------- launcher ----------------
extern "C" void kernel_launch(void* const* d_in, const int* in_sizes, int n_in,
                              void* d_out, int out_size, void* d_ws, size_t ws_size,
                              hipStream_t stream) {
  const float* x = (const float*)d_in[0];
  const float* Wq = (const float*)d_in[1];
  const float* Wkv = (const float*)d_in[2];
  const float* Wo = (const float*)d_in[3];
  float* out = (float*)d_out;

  bf16* xb = (bf16*)d_ws;                          // 8192*2048
  bf16* Wqb = xb + (size_t)NROWS * DIMM;           // 2048*2048
  bf16* Wkvb = Wqb + (size_t)DIMM * DIMM;          // 1024*2048
  bf16* Wob = Wkvb + (size_t)2 * NKV * HD * DIMM;  // 2048*2048
  bf16* attn = Wob + (size_t)DIMM * DIMM;          // 8192*2048
  bf16* qkv = (bf16*)d_out;  // 50.3MB scratch inside 67.1MB d_out

  cvt_f32_bf16<<<2048, 256, 0, stream>>>(x, xb, NROWS * DIMM);
  cvt_f32_bf16<<<1024, 256, 0, stream>>>(Wq, Wqb, DIMM * DIMM);
  cvt_f32_bf16<<<512, 256, 0, stream>>>(Wkv, Wkvb, 2 * NKV * HD * DIMM);
  cvt_f32_bf16<<<1024, 256, 0, stream>>>(Wo, Wob, DIMM * DIMM);

  gemm_bt<bf16><<<dim3(NROWS / 128, QKVN / 128), 256, 0, stream>>>(
      xb, Wqb, Wkvb, qkv, NROWS, QKVN, DIMM, DIMM);

  rope_kernel<<<(NROWS * 20 * 64) / 256, 256, 0, stream>>>(qkv);

  attn_kernel<<<dim3(SEQ / 64, BATCH * NHEAD), 256, 0, stream>>>(qkv, attn);

  gemm_bt<float><<<dim3(NROWS / 128, DIMM / 128), 256, 0, stream>>>(
      attn, Wob, Wob, out, NROWS, DIMM, DIMM, DIMM);
}

// Round 5
// 452.156 us; speedup vs baseline: 2.2212x; 1.4977x over previous
//
#include <hip/hip_runtime.h>
#include <hip/hip_bf16.h>

typedef __hip_bfloat16 bf16;
typedef __attribute__((ext_vector_type(4))) float f32x4;
typedef __attribute__((ext_vector_type(16))) float f32x16;
typedef __attribute__((ext_vector_type(8))) short short8;
typedef __attribute__((ext_vector_type(4))) unsigned u32x4;

#define NHEAD 16
#define NKV 4
#define HD 128
#define BATCH 4
#define SEQ 2048
#define DIMM 2048
#define NROWS (BATCH*SEQ)        // 8192
#define QKVN (DIMM + 2*NKV*HD)   // 3072

__device__ inline void gload_lds16(const bf16* g, bf16* l) {
  __builtin_amdgcn_global_load_lds(
      (const __attribute__((address_space(1))) unsigned int*)g,
      (__attribute__((address_space(3))) unsigned int*)l, 16, 0, 0);
}

__device__ inline unsigned cvtpk(float a, float b) {
  unsigned r;
  asm("v_cvt_pk_bf16_f32 %0, %1, %2" : "=v"(r) : "v"(a), "v"(b));
  return r;
}
__device__ inline void pswap(unsigned& x, unsigned& y) {
  // vdst[32+i] <-> vsrc[i]: x' = {x_lo, y_lo}, y' = {x_hi, y_hi}
  asm volatile("v_permlane32_swap_b32 %0, %1" : "+v"(x), "+v"(y));
}

// ---------------- fp32 -> bf16 conversion ----------------
__global__ void cvt_f32_bf16(const float* __restrict__ s, bf16* __restrict__ d, int n) {
  for (int i = (blockIdx.x * blockDim.x + threadIdx.x) * 4; i < n;
       i += gridDim.x * blockDim.x * 4) {
    const float4 v = *reinterpret_cast<const float4*>(s + i);
    alignas(8) bf16 t[4] = {__float2bfloat16(v.x), __float2bfloat16(v.y),
                            __float2bfloat16(v.z), __float2bfloat16(v.w)};
    *reinterpret_cast<uint2*>(d + i) = *reinterpret_cast<const uint2*>(t);
  }
}

// ---------------- GEMM: C[M][N] = A[M][K] * B[N][K]^T (bf16, fp32 accum) ----------------
__device__ inline void store_c(float* p, float v) { *p = v; }
__device__ inline void store_c(bf16* p, float v) { *p = __float2bfloat16(v); }

template <typename OutT>
__global__ __launch_bounds__(256) void gemm_bt(
    const bf16* __restrict__ A, const bf16* __restrict__ B0,
    const bf16* __restrict__ B1, OutT* __restrict__ C,
    int M, int N, int K, int Nsplit) {
  __shared__ __align__(16) bf16 As[128 * 64];
  __shared__ __align__(16) bf16 Bs[128 * 64];
  const int tid = threadIdx.x;
  const int w = tid >> 6, l = tid & 63;
  const int m0 = blockIdx.x * 128, n0 = blockIdx.y * 128;
  const bf16* Ap = A + (size_t)m0 * K;
  const bf16* Bp = (n0 < Nsplit) ? (B0 + (size_t)n0 * K)
                                 : (B1 + (size_t)(n0 - Nsplit) * K);
  const int wm = (w >> 1) * 64, wn = (w & 1) * 64;
  const int lr = l & 15, lk = (l >> 4) * 8;

  f32x4 acc[4][4] = {};

  for (int kt = 0; kt < K; kt += 64) {
#pragma unroll
    for (int i = 0; i < 4; ++i) {
      const int c = w * 64 + i * 256;
      const int cc = c + l;
      const int row = cc >> 3, ci = cc & 7;
      gload_lds16(Ap + (size_t)row * K + kt + ci * 8, &As[c * 8]);
      gload_lds16(Bp + (size_t)row * K + kt + ci * 8, &Bs[c * 8]);
    }
    __syncthreads();
#pragma unroll
    for (int kk = 0; kk < 2; ++kk) {
      short8 a[4], b[4];
#pragma unroll
      for (int t = 0; t < 4; ++t) {
        a[t] = *(const short8*)&As[(wm + t * 16 + lr) * 64 + kk * 32 + lk];
        b[t] = *(const short8*)&Bs[(wn + t * 16 + lr) * 64 + kk * 32 + lk];
      }
#pragma unroll
      for (int mt = 0; mt < 4; ++mt)
#pragma unroll
        for (int nt = 0; nt < 4; ++nt)
          acc[mt][nt] = __builtin_amdgcn_mfma_f32_16x16x32_bf16(
              a[mt], b[nt], acc[mt][nt], 0, 0, 0);
    }
    __syncthreads();
  }

  const int cr = (l >> 4) * 4;
#pragma unroll
  for (int mt = 0; mt < 4; ++mt)
#pragma unroll
    for (int nt = 0; nt < 4; ++nt)
#pragma unroll
      for (int r = 0; r < 4; ++r) {
        const int row = m0 + wm + mt * 16 + cr + r;
        const int col = n0 + wn + nt * 16 + lr;
        store_c(&C[(size_t)row * N + col], acc[mt][nt][r]);
      }
}

// ---------------- RoPE (q heads get prescale = 1/sqrt(128)*log2(e)) ----------------
__global__ void rope_kernel(bf16* __restrict__ qkv) {
  const int idx = blockIdx.x * blockDim.x + threadIdx.x;
  const int total = NROWS * 20 * 64;
  if (idx >= total) return;
  const int d = idx & 63;
  const int slot = (idx >> 6) % 20;
  const int row = idx / (64 * 20);
  const int col = (slot < 16) ? slot * 128 : DIMM + (slot - 16) * 128;
  const size_t base = (size_t)row * QKVN + col;
  const int pos = row & (SEQ - 1);
  const float inv = exp2f((float)d * (-2.0f / 128.0f) * 13.287712379549449f);
  const float ang = (float)pos * inv;
  float sn, cs;
  __sincosf(ang, &sn, &cs);
  const float psc = (slot < 16) ? 0.12751879895f : 1.0f;  // scale*log2e for Q only
  const float lo = __bfloat162float(qkv[base + d]);
  const float hi = __bfloat162float(qkv[base + d + 64]);
  qkv[base + d] = __float2bfloat16((lo * cs - hi * sn) * psc);
  qkv[base + d + 64] = __float2bfloat16((hi * cs + lo * sn) * psc);
}

// ---------------- V transpose: qkv V-part -> vtg[kvh][d][b*SEQ+s] ----------------
__global__ __launch_bounds__(256) void vtrans_kernel(const bf16* __restrict__ qkv,
                                                     bf16* __restrict__ vtg) {
  __shared__ short T[64 * 72];
  const int si = blockIdx.x * 64;
  const int di = blockIdx.y * 64;
  const int b = blockIdx.z >> 2, kvh = blockIdx.z & 3;
  const int t = threadIdx.x;
  const int r = t >> 2, c2 = (t & 3) * 2;
  const bf16* src =
      qkv + (size_t)(b * SEQ + si + r) * QKVN + DIMM + NKV * HD + kvh * 128 + di;
#pragma unroll
  for (int i = 0; i < 2; ++i)
    *(short8*)&T[r * 72 + (c2 + i) * 8] = *(const short8*)(src + (c2 + i) * 8);
  __syncthreads();
#pragma unroll
  for (int i = 0; i < 2; ++i) {
    short8 v;
    const int s8 = (c2 + i) * 8;
#pragma unroll
    for (int j = 0; j < 8; ++j) v[j] = T[(s8 + j) * 72 + r];
    *(short8*)(vtg + (size_t)(kvh * 128 + di + r) * NROWS + b * SEQ + si + s8) = v;
  }
}

// ---------------- Flash attention: 8 waves x 32 q-rows, KVBLK=64, swapped QK^T ----
// grid (8, B*NHEAD), 512 threads. K LDS [64][128], Vt LDS [128][64], both
// double-buffered, XOR-chunk-swizzled via pre-swizzled global source.
__global__ __launch_bounds__(512, 2) void attn_kernel(
    const bf16* __restrict__ qkv, const bf16* __restrict__ vtg,
    bf16* __restrict__ aout) {
  __shared__ __align__(16) short KsL[2][64 * 128];
  __shared__ __align__(16) short VtL[2][128 * 64];
  const int tid = threadIdx.x, w = tid >> 6, l = tid & 63;
  const int lq = l & 31, hi = l >> 5;
  const int qb = 7 - (int)blockIdx.x;  // longest first
  const int bh = blockIdx.y;
  const int b = bh >> 4, h = bh & 15, kvh = h >> 2;
  const int qw0 = qb * 256 + w * 32;   // warp's first q row
  const int qg = qw0 + lq;             // this lane's q row (ST col)

  // Q B-frags (already prescaled by scale*log2e in rope): qf[s] = Q[q][16s+8hi..+8]
  short8 qf[8];
  {
    const bf16* qptr = qkv + (size_t)(b * SEQ + qg) * QKVN + h * 128 + hi * 8;
#pragma unroll
    for (int s = 0; s < 8; ++s) qf[s] = *(const short8*)(qptr + s * 16);
  }

  f32x16 o[4] = {};            // d-block db: lane holds O[q=crow(r,hi)][d=db*32+lq]
  float m = -1e30f, lsum = 0.f;
  const int ntiles = qb * 4 + 4;

  const bf16* Kgb = qkv + (size_t)(b * SEQ) * QKVN + DIMM + kvh * 128;
  const bf16* Vgb = vtg + (size_t)kvh * 128 * NROWS + b * SEQ;

  auto stage = [&](int kt, int buf) {
#pragma unroll
    for (int rd = 0; rd < 2; ++rd) {
      const int cb = (w * 2 + rd) * 64;
      {
        const int lc = cb + l, k = lc >> 4, c = lc & 15;
        gload_lds16(Kgb + (size_t)(kt * 64 + k) * QKVN + ((c ^ (k & 7)) * 8),
                    (bf16*)&KsL[buf][cb * 8]);
      }
      {
        const int lc = cb + l, d = lc >> 3, c = lc & 7;
        gload_lds16(Vgb + (size_t)d * NROWS + kt * 64 + ((c ^ (d & 7)) * 8),
                    (bf16*)&VtL[buf][cb * 8]);
      }
    }
  };

  stage(0, 0);
  asm volatile("s_waitcnt vmcnt(0)" ::: "memory");
  __builtin_amdgcn_s_barrier();
  __builtin_amdgcn_sched_barrier(0);

  for (int kt = 0; kt < ntiles; ++kt) {
    const int cur = kt & 1;
    if (kt + 1 < ntiles) stage(kt + 1, cur ^ 1);

    if (kt * 64 <= qw0 + 31) {  // warp has live keys in this tile
      // ST = K·Q^T : lane owns q=lq; reg r of ksub holds k = ksub*32+crow(r,hi)
      f32x16 st[2];
#pragma unroll
      for (int ks = 0; ks < 2; ++ks) {
        const short* kb = &KsL[cur][(ks * 32 + lq) * 128];
        const int r7 = lq & 7;
        f32x16 acc = {};
#pragma unroll
        for (int s = 0; s < 8; ++s) {
          const short8 kf = *(const short8*)&kb[((2 * s + hi) ^ r7) * 8];
          acc = __builtin_amdgcn_mfma_f32_32x32x16_bf16(kf, qf[s], acc, 0, 0, 0);
        }
        st[ks] = acc;
      }
      // causal mask (diagonal tiles only)
      if (kt * 64 + 63 > qw0) {
#pragma unroll
        for (int ks = 0; ks < 2; ++ks)
#pragma unroll
          for (int r = 0; r < 16; ++r) {
            const int kg = kt * 64 + ks * 32 + (r & 3) + 8 * (r >> 2) + 4 * hi;
            if (kg > qg) st[ks][r] = -1e30f;
          }
      }
      // row max: in-lane tree + half exchange
      float t[16];
#pragma unroll
      for (int r = 0; r < 16; ++r) t[r] = fmaxf(st[0][r], st[1][r]);
#pragma unroll
      for (int d2 = 8; d2 > 0; d2 >>= 1)
#pragma unroll
        for (int r = 0; r < 8; ++r)
          if (r < d2) t[r] = fmaxf(t[r], t[r + d2]);
      float pm = fmaxf(t[0], __shfl_xor(t[0], 32));
      // defer-max (log2 domain, THR=11)
      if (!__all(pm <= m + 11.0f)) {
        const float mnew = fmaxf(m, pm);
        const float fsc = __builtin_amdgcn_exp2f(m - mnew);
        m = mnew;
        lsum *= fsc;
#pragma unroll
        for (int r = 0; r < 16; ++r) {
          const float fq = __shfl(fsc, (r & 3) + 8 * (r >> 2) + 4 * hi);
#pragma unroll
          for (int db = 0; db < 4; ++db) o[db][r] *= fq;
        }
      }
      // P = exp2(ST - m), pack to A-frags via cvt_pk + permlane32_swap
      short8 pa[4];
#pragma unroll
      for (int ks = 0; ks < 2; ++ks) {
        float p[16];
        float s0 = 0.f, s1 = 0.f, s2 = 0.f, s3 = 0.f;
#pragma unroll
        for (int r = 0; r < 16; r += 4) {
          p[r] = __builtin_amdgcn_exp2f(st[ks][r] - m);         s0 += p[r];
          p[r + 1] = __builtin_amdgcn_exp2f(st[ks][r + 1] - m); s1 += p[r + 1];
          p[r + 2] = __builtin_amdgcn_exp2f(st[ks][r + 2] - m); s2 += p[r + 2];
          p[r + 3] = __builtin_amdgcn_exp2f(st[ks][r + 3] - m); s3 += p[r + 3];
        }
        lsum += (s0 + s1) + (s2 + s3);
#pragma unroll
        for (int hf = 0; hf < 2; ++hf) {
          unsigned x0 = cvtpk(p[hf * 8 + 0], p[hf * 8 + 1]);
          unsigned y0 = cvtpk(p[hf * 8 + 4], p[hf * 8 + 5]);
          unsigned x1 = cvtpk(p[hf * 8 + 2], p[hf * 8 + 3]);
          unsigned y1 = cvtpk(p[hf * 8 + 6], p[hf * 8 + 7]);
          pswap(x0, y0);  // x0 -> word0 (k j0..1), y0 -> word2 (k j4..5)
          pswap(x1, y1);  // x1 -> word1, y1 -> word3
          union { u32x4 u; short8 s; } pk;
          pk.u = u32x4{x0, x1, y0, y1};
          pa[ks * 2 + hf] = pk.s;
        }
      }
      // PV: O[q][d] += P·V, 4 k-steps x 4 d-blocks
#pragma unroll
      for (int s = 0; s < 4; ++s) {
        const int cc = ((2 * s + hi) ^ (lq & 7)) * 8;
#pragma unroll
        for (int db = 0; db < 4; ++db) {
          const short8 vb = *(const short8*)&VtL[cur][(db * 32 + lq) * 64 + cc];
          o[db] = __builtin_amdgcn_mfma_f32_32x32x16_bf16(pa[s], vb, o[db], 0, 0, 0);
        }
      }
    }

    asm volatile("s_waitcnt vmcnt(0)" ::: "memory");  // next tile staged
    __builtin_amdgcn_s_barrier();
    __builtin_amdgcn_sched_barrier(0);
  }

  // finalize: full row-sum, redistribute to O layout, write
  const float lf = lsum + __shfl_xor(lsum, 32);
#pragma unroll
  for (int r = 0; r < 16; ++r) {
    const int qr = (r & 3) + 8 * (r >> 2) + 4 * hi;
    const float linv = 1.0f / __shfl(lf, qr);
    bf16* op = aout + (size_t)(b * SEQ + qw0 + qr) * DIMM + h * 128 + lq;
#pragma unroll
    for (int db = 0; db < 4; ++db)
      op[db * 32] = __float2bfloat16(o[db][r] * linv);
  }
}

// ---------------- launcher ----------------
extern "C" void kernel_launch(void* const* d_in, const int* in_sizes, int n_in,
                              void* d_out, int out_size, void* d_ws, size_t ws_size,
                              hipStream_t stream) {
  const float* x = (const float*)d_in[0];
  const float* Wq = (const float*)d_in[1];
  const float* Wkv = (const float*)d_in[2];
  const float* Wo = (const float*)d_in[3];
  float* out = (float*)d_out;

  bf16* xb = (bf16*)d_ws;                          // 8192*2048
  bf16* Wqb = xb + (size_t)NROWS * DIMM;           // 2048*2048
  bf16* Wkvb = Wqb + (size_t)DIMM * DIMM;          // 1024*2048
  bf16* Wob = Wkvb + (size_t)2 * NKV * HD * DIMM;  // 2048*2048
  bf16* attn = Wob + (size_t)DIMM * DIMM;          // 8192*2048
  bf16* qkv = (bf16*)d_out;                        // 50.3MB scratch in d_out
  bf16* vtg = (bf16*)d_out + (size_t)NROWS * QKVN; // 8MB more, still in d_out

  cvt_f32_bf16<<<2048, 256, 0, stream>>>(x, xb, NROWS * DIMM);
  cvt_f32_bf16<<<1024, 256, 0, stream>>>(Wq, Wqb, DIMM * DIMM);
  cvt_f32_bf16<<<512, 256, 0, stream>>>(Wkv, Wkvb, 2 * NKV * HD * DIMM);
  cvt_f32_bf16<<<1024, 256, 0, stream>>>(Wo, Wob, DIMM * DIMM);

  gemm_bt<bf16><<<dim3(NROWS / 128, QKVN / 128), 256, 0, stream>>>(
      xb, Wqb, Wkvb, qkv, NROWS, QKVN, DIMM, DIMM);

  rope_kernel<<<(NROWS * 20 * 64) / 256, 256, 0, stream>>>(qkv);

  vtrans_kernel<<<dim3(SEQ / 64, 2, 16), 256, 0, stream>>>(qkv, vtg);

  attn_kernel<<<dim3(8, BATCH * NHEAD), 512, 0, stream>>>(qkv, vtg, attn);

  gemm_bt<float><<<dim3(NROWS / 128, DIMM / 128), 256, 0, stream>>>(
      attn, Wob, Wob, out, NROWS, DIMM, DIMM, DIMM);
}

// Round 6
// 327.500 us; speedup vs baseline: 3.0667x; 1.3806x over previous
//
#include <hip/hip_runtime.h>
#include <hip/hip_bf16.h>

typedef __hip_bfloat16 bf16;
typedef __attribute__((ext_vector_type(4))) float f32x4;
typedef __attribute__((ext_vector_type(16))) float f32x16;
typedef __attribute__((ext_vector_type(8))) short short8;
typedef __attribute__((ext_vector_type(4))) unsigned u32x4;

#define NHEAD 16
#define NKV 4
#define HD 128
#define BATCH 4
#define SEQ 2048
#define DIMM 2048
#define NROWS (BATCH*SEQ)        // 8192
#define QKVN (DIMM + 2*NKV*HD)   // 3072

__device__ inline void gload_lds16(const bf16* g, bf16* l) {
  __builtin_amdgcn_global_load_lds(
      (const __attribute__((address_space(1))) unsigned int*)g,
      (__attribute__((address_space(3))) unsigned int*)l, 16, 0, 0);
}

__device__ inline unsigned cvtpk(float a, float b) {
  unsigned r;
  asm("v_cvt_pk_bf16_f32 %0, %1, %2" : "=v"(r) : "v"(a), "v"(b));
  return r;
}
__device__ inline void pswap(unsigned& x, unsigned& y) {
  asm volatile("v_permlane32_swap_b32 %0, %1" : "+v"(x), "+v"(y));
}

// ---------------- fp32 -> bf16 conversion ----------------
__global__ void cvt_f32_bf16(const float* __restrict__ s, bf16* __restrict__ d, int n) {
  for (int i = (blockIdx.x * blockDim.x + threadIdx.x) * 4; i < n;
       i += gridDim.x * blockDim.x * 4) {
    const float4 v = *reinterpret_cast<const float4*>(s + i);
    alignas(8) bf16 t[4] = {__float2bfloat16(v.x), __float2bfloat16(v.y),
                            __float2bfloat16(v.z), __float2bfloat16(v.w)};
    *reinterpret_cast<uint2*>(d + i) = *reinterpret_cast<const uint2*>(t);
  }
}

__device__ inline void store_c(float* p, float v) { *p = v; }
__device__ inline void store_c(bf16* p, float v) { *p = __float2bfloat16(v); }

// ---------------- GEMM 256x256 tile, BK=64, 8 waves, pipelined (T2+T3+T4+T5) ----
// C[M][N] = A[M][K] * B[N][K]^T. 4 LDS planes (2 buf x 2 khalf) per operand.
// Per sub-phase: entry vmcnt(8)+barrier, 12 ds_read_b128, stage 1 group
// (4 gload_lds, 3 groups in flight), lgkmcnt(0), 32 MFMA under setprio.
// LDS chunk swizzle c ^= (row&3)^((row>>2)&1) applied on BOTH sides.
template <typename OutT>
__global__ __launch_bounds__(512, 2) void gemm256(
    const bf16* __restrict__ A, const bf16* __restrict__ B0,
    const bf16* __restrict__ B1, OutT* __restrict__ C,
    int M, int N, int K, int Nsplit) {
  __shared__ __align__(16) short As[2][2][256 * 32];
  __shared__ __align__(16) short Bs[2][2][256 * 32];
  const int tid = threadIdx.x;
  const int w = tid >> 6, l = tid & 63;
  const int m0 = blockIdx.x * 256, n0 = blockIdx.y * 256;
  const bf16* Ap = A + (size_t)m0 * K;
  const bf16* Bp = (n0 < Nsplit) ? (B0 + (size_t)n0 * K)
                                 : (B1 + (size_t)(n0 - Nsplit) * K);
  const int wr = w >> 2, wc = w & 3;  // wave grid 2(M) x 4(N)
  const int lr = l & 15, lc = l >> 4;
  const int swz = lc ^ (l & 3) ^ ((l >> 2) & 1);  // read-side chunk swizzle

  f32x4 acc[8][4] = {};
  const int KT = K >> 6;

  // stage {A,B} khalf kh of K-tile kt into buffer buf (4 loads/thread)
  auto stage = [&](int kt, int kh, int buf) {
#pragma unroll
    for (int j = 0; j < 2; ++j) {
      const int cbase = j * 512 + w * 64;  // wave-uniform chunk base
      const int ch = cbase + l;
      const int row = ch >> 2, c = ch & 3;
      const int sc = c ^ (row & 3) ^ ((row >> 2) & 1);
      const int gcol = kt * 64 + kh * 32 + sc * 8;
      gload_lds16(Ap + (size_t)row * K + gcol, (bf16*)&As[buf][kh][cbase * 8]);
      gload_lds16(Bp + (size_t)row * K + gcol, (bf16*)&Bs[buf][kh][cbase * 8]);
    }
  };

  // prologue: groups g0,g1,g2
  stage(0, 0, 0);
  stage(0, 1, 0);
  stage(1, 0, 1);

  for (int kt = 0; kt < KT; ++kt) {
    const int cur = kt & 1;
#pragma unroll
    for (int kh = 0; kh < 2; ++kh) {
      if (kt < KT - 1) {
        asm volatile("s_waitcnt vmcnt(8)" ::: "memory");
      } else if (kh == 0) {
        asm volatile("s_waitcnt vmcnt(4)" ::: "memory");
      } else {
        asm volatile("s_waitcnt vmcnt(0)" ::: "memory");
      }
      __builtin_amdgcn_s_barrier();
      __builtin_amdgcn_sched_barrier(0);

      short8 a[8], b[4];
      const short* Ab = &As[cur][kh][0];
      const short* Bb = &Bs[cur][kh][0];
#pragma unroll
      for (int mr = 0; mr < 8; ++mr)
        a[mr] = *(const short8*)&Ab[(wr * 128 + mr * 16 + lr) * 32 + swz * 8];
#pragma unroll
      for (int nr = 0; nr < 4; ++nr)
        b[nr] = *(const short8*)&Bb[(wc * 64 + nr * 16 + lr) * 32 + swz * 8];

      // stage group g = 2kt+kh+3 (tile g>>1, khalf g&1, buf (g>>1)&1)
      {
        const int g = 2 * kt + kh + 3;
        const int st = g >> 1;
        if (st < KT) stage(st, g & 1, st & 1);
      }

      asm volatile("s_waitcnt lgkmcnt(0)" ::: "memory");
      __builtin_amdgcn_sched_barrier(0);
      __builtin_amdgcn_s_setprio(1);
#pragma unroll
      for (int mr = 0; mr < 8; ++mr)
#pragma unroll
        for (int nr = 0; nr < 4; ++nr)
          acc[mr][nr] = __builtin_amdgcn_mfma_f32_16x16x32_bf16(
              a[mr], b[nr], acc[mr][nr], 0, 0, 0);
      __builtin_amdgcn_s_setprio(0);
    }
  }

  const int cr4 = (l >> 4) * 4;
#pragma unroll
  for (int mr = 0; mr < 8; ++mr)
#pragma unroll
    for (int nr = 0; nr < 4; ++nr)
#pragma unroll
      for (int r = 0; r < 4; ++r) {
        const int row = m0 + wr * 128 + mr * 16 + cr4 + r;
        const int col = n0 + wc * 64 + nr * 16 + lr;
        store_c(&C[(size_t)row * N + col], acc[mr][nr][r]);
      }
}

// ---------------- RoPE (q heads get prescale = 1/sqrt(128)*log2(e)) ----------------
__global__ void rope_kernel(bf16* __restrict__ qkv) {
  const int idx = blockIdx.x * blockDim.x + threadIdx.x;
  const int total = NROWS * 20 * 64;
  if (idx >= total) return;
  const int d = idx & 63;
  const int slot = (idx >> 6) % 20;
  const int row = idx / (64 * 20);
  const int col = (slot < 16) ? slot * 128 : DIMM + (slot - 16) * 128;
  const size_t base = (size_t)row * QKVN + col;
  const int pos = row & (SEQ - 1);
  const float inv = exp2f((float)d * (-2.0f / 128.0f) * 13.287712379549449f);
  const float ang = (float)pos * inv;
  float sn, cs;
  __sincosf(ang, &sn, &cs);
  const float psc = (slot < 16) ? 0.12751879895f : 1.0f;  // scale*log2e for Q only
  const float lo = __bfloat162float(qkv[base + d]);
  const float hi = __bfloat162float(qkv[base + d + 64]);
  qkv[base + d] = __float2bfloat16((lo * cs - hi * sn) * psc);
  qkv[base + d + 64] = __float2bfloat16((hi * cs + lo * sn) * psc);
}

// ---------------- V transpose: qkv V-part -> vtg[kvh][d][b*SEQ+s] ----------------
__global__ __launch_bounds__(256) void vtrans_kernel(const bf16* __restrict__ qkv,
                                                     bf16* __restrict__ vtg) {
  __shared__ short T[64 * 72];
  const int si = blockIdx.x * 64;
  const int di = blockIdx.y * 64;
  const int b = blockIdx.z >> 2, kvh = blockIdx.z & 3;
  const int t = threadIdx.x;
  const int r = t >> 2, c2 = (t & 3) * 2;
  const bf16* src =
      qkv + (size_t)(b * SEQ + si + r) * QKVN + DIMM + NKV * HD + kvh * 128 + di;
#pragma unroll
  for (int i = 0; i < 2; ++i)
    *(short8*)&T[r * 72 + (c2 + i) * 8] = *(const short8*)(src + (c2 + i) * 8);
  __syncthreads();
#pragma unroll
  for (int i = 0; i < 2; ++i) {
    short8 v;
    const int s8 = (c2 + i) * 8;
#pragma unroll
    for (int j = 0; j < 8; ++j) v[j] = T[(s8 + j) * 72 + r];
    *(short8*)(vtg + (size_t)(kvh * 128 + di + r) * NROWS + b * SEQ + si + s8) = v;
  }
}

// ---------------- Flash attention: 8 waves x 32 q-rows, KVBLK=64, swapped QK^T ----
// grid 512 (1D, pair-balanced: co-resident blocks id,id+256 get qb=(7-j,j) so
// every CU's tile-work sums to ~36), 512 threads.
__global__ __launch_bounds__(512, 2) void attn_kernel(
    const bf16* __restrict__ qkv, const bf16* __restrict__ vtg,
    bf16* __restrict__ aout) {
  __shared__ __align__(16) short KsL[2][64 * 128];
  __shared__ __align__(16) short VtL[2][128 * 64];
  const int tid = threadIdx.x, w = tid >> 6, l = tid & 63;
  const int lq = l & 31, hi = l >> 5;
  const int id = blockIdx.x;
  const int half = id >> 8, rr = id & 255;
  const int bh = (rr >> 3) + half * 32;
  const int j = rr & 7;
  const int qb = half ? j : 7 - j;
  const int b = bh >> 4, h = bh & 15, kvh = h >> 2;
  const int qw0 = qb * 256 + w * 32;   // warp's first q row
  const int qg = qw0 + lq;             // this lane's q row (ST col)

  short8 qf[8];
  {
    const bf16* qptr = qkv + (size_t)(b * SEQ + qg) * QKVN + h * 128 + hi * 8;
#pragma unroll
    for (int s = 0; s < 8; ++s) qf[s] = *(const short8*)(qptr + s * 16);
  }

  f32x16 o[4] = {};
  float m = -1e30f, lsum = 0.f;
  const int ntiles = qb * 4 + 4;

  const bf16* Kgb = qkv + (size_t)(b * SEQ) * QKVN + DIMM + kvh * 128;
  const bf16* Vgb = vtg + (size_t)kvh * 128 * NROWS + b * SEQ;

  auto stage = [&](int kt, int buf) {
#pragma unroll
    for (int rd = 0; rd < 2; ++rd) {
      const int cb = (w * 2 + rd) * 64;
      {
        const int lc = cb + l, k = lc >> 4, c = lc & 15;
        gload_lds16(Kgb + (size_t)(kt * 64 + k) * QKVN + ((c ^ (k & 7)) * 8),
                    (bf16*)&KsL[buf][cb * 8]);
      }
      {
        const int lc = cb + l, d = lc >> 3, c = lc & 7;
        gload_lds16(Vgb + (size_t)d * NROWS + kt * 64 + ((c ^ (d & 7)) * 8),
                    (bf16*)&VtL[buf][cb * 8]);
      }
    }
  };

  stage(0, 0);
  asm volatile("s_waitcnt vmcnt(0)" ::: "memory");
  __builtin_amdgcn_s_barrier();
  __builtin_amdgcn_sched_barrier(0);

  for (int kt = 0; kt < ntiles; ++kt) {
    const int cur = kt & 1;
    if (kt + 1 < ntiles) stage(kt + 1, cur ^ 1);

    if (kt * 64 <= qw0 + 31) {
      f32x16 st[2];
#pragma unroll
      for (int ks = 0; ks < 2; ++ks) {
        const short* kb = &KsL[cur][(ks * 32 + lq) * 128];
        const int r7 = lq & 7;
        f32x16 acc = {};
#pragma unroll
        for (int s = 0; s < 8; ++s) {
          const short8 kf = *(const short8*)&kb[((2 * s + hi) ^ r7) * 8];
          acc = __builtin_amdgcn_mfma_f32_32x32x16_bf16(kf, qf[s], acc, 0, 0, 0);
        }
        st[ks] = acc;
      }
      if (kt * 64 + 63 > qw0) {
#pragma unroll
        for (int ks = 0; ks < 2; ++ks)
#pragma unroll
          for (int r = 0; r < 16; ++r) {
            const int kg = kt * 64 + ks * 32 + (r & 3) + 8 * (r >> 2) + 4 * hi;
            if (kg > qg) st[ks][r] = -1e30f;
          }
      }
      float t[16];
#pragma unroll
      for (int r = 0; r < 16; ++r) t[r] = fmaxf(st[0][r], st[1][r]);
#pragma unroll
      for (int d2 = 8; d2 > 0; d2 >>= 1)
#pragma unroll
        for (int r = 0; r < 8; ++r)
          if (r < d2) t[r] = fmaxf(t[r], t[r + d2]);
      float pm = fmaxf(t[0], __shfl_xor(t[0], 32));
      if (!__all(pm <= m + 11.0f)) {
        const float mnew = fmaxf(m, pm);
        const float fsc = __builtin_amdgcn_exp2f(m - mnew);
        m = mnew;
        lsum *= fsc;
#pragma unroll
        for (int r = 0; r < 16; ++r) {
          const float fq = __shfl(fsc, (r & 3) + 8 * (r >> 2) + 4 * hi);
#pragma unroll
          for (int db = 0; db < 4; ++db) o[db][r] *= fq;
        }
      }
      short8 pa[4];
#pragma unroll
      for (int ks = 0; ks < 2; ++ks) {
        float p[16];
        float s0 = 0.f, s1 = 0.f, s2 = 0.f, s3 = 0.f;
#pragma unroll
        for (int r = 0; r < 16; r += 4) {
          p[r] = __builtin_amdgcn_exp2f(st[ks][r] - m);         s0 += p[r];
          p[r + 1] = __builtin_amdgcn_exp2f(st[ks][r + 1] - m); s1 += p[r + 1];
          p[r + 2] = __builtin_amdgcn_exp2f(st[ks][r + 2] - m); s2 += p[r + 2];
          p[r + 3] = __builtin_amdgcn_exp2f(st[ks][r + 3] - m); s3 += p[r + 3];
        }
        lsum += (s0 + s1) + (s2 + s3);
#pragma unroll
        for (int hf = 0; hf < 2; ++hf) {
          unsigned x0 = cvtpk(p[hf * 8 + 0], p[hf * 8 + 1]);
          unsigned y0 = cvtpk(p[hf * 8 + 4], p[hf * 8 + 5]);
          unsigned x1 = cvtpk(p[hf * 8 + 2], p[hf * 8 + 3]);
          unsigned y1 = cvtpk(p[hf * 8 + 6], p[hf * 8 + 7]);
          pswap(x0, y0);
          pswap(x1, y1);
          union { u32x4 u; short8 s; } pk;
          pk.u = u32x4{x0, x1, y0, y1};
          pa[ks * 2 + hf] = pk.s;
        }
      }
#pragma unroll
      for (int s = 0; s < 4; ++s) {
        const int cc = ((2 * s + hi) ^ (lq & 7)) * 8;
#pragma unroll
        for (int db = 0; db < 4; ++db) {
          const short8 vb = *(const short8*)&VtL[cur][(db * 32 + lq) * 64 + cc];
          o[db] = __builtin_amdgcn_mfma_f32_32x32x16_bf16(pa[s], vb, o[db], 0, 0, 0);
        }
      }
    }

    asm volatile("s_waitcnt vmcnt(0)" ::: "memory");
    __builtin_amdgcn_s_barrier();
    __builtin_amdgcn_sched_barrier(0);
  }

  const float lf = lsum + __shfl_xor(lsum, 32);
#pragma unroll
  for (int r = 0; r < 16; ++r) {
    const int qr = (r & 3) + 8 * (r >> 2) + 4 * hi;
    const float linv = 1.0f / __shfl(lf, qr);
    bf16* op = aout + (size_t)(b * SEQ + qw0 + qr) * DIMM + h * 128 + lq;
#pragma unroll
    for (int db = 0; db < 4; ++db)
      op[db * 32] = __float2bfloat16(o[db][r] * linv);
  }
}

// ---------------- launcher ----------------
extern "C" void kernel_launch(void* const* d_in, const int* in_sizes, int n_in,
                              void* d_out, int out_size, void* d_ws, size_t ws_size,
                              hipStream_t stream) {
  const float* x = (const float*)d_in[0];
  const float* Wq = (const float*)d_in[1];
  const float* Wkv = (const float*)d_in[2];
  const float* Wo = (const float*)d_in[3];
  float* out = (float*)d_out;

  bf16* xb = (bf16*)d_ws;                          // 8192*2048
  bf16* Wqb = xb + (size_t)NROWS * DIMM;           // 2048*2048
  bf16* Wkvb = Wqb + (size_t)DIMM * DIMM;          // 1024*2048
  bf16* Wob = Wkvb + (size_t)2 * NKV * HD * DIMM;  // 2048*2048
  bf16* attn = Wob + (size_t)DIMM * DIMM;          // 8192*2048
  bf16* qkv = (bf16*)d_out;                        // 50.3MB scratch in d_out
  bf16* vtg = (bf16*)d_out + (size_t)NROWS * QKVN; // 8MB more, still in d_out

  cvt_f32_bf16<<<2048, 256, 0, stream>>>(x, xb, NROWS * DIMM);
  cvt_f32_bf16<<<1024, 256, 0, stream>>>(Wq, Wqb, DIMM * DIMM);
  cvt_f32_bf16<<<512, 256, 0, stream>>>(Wkv, Wkvb, 2 * NKV * HD * DIMM);
  cvt_f32_bf16<<<1024, 256, 0, stream>>>(Wo, Wob, DIMM * DIMM);

  gemm256<bf16><<<dim3(NROWS / 256, QKVN / 256), 512, 0, stream>>>(
      xb, Wqb, Wkvb, qkv, NROWS, QKVN, DIMM, DIMM);

  rope_kernel<<<(NROWS * 20 * 64) / 256, 256, 0, stream>>>(qkv);

  vtrans_kernel<<<dim3(SEQ / 64, 2, 16), 256, 0, stream>>>(qkv, vtg);

  attn_kernel<<<dim3(512), 512, 0, stream>>>(qkv, vtg, attn);

  gemm256<float><<<dim3(NROWS / 256, DIMM / 256), 512, 0, stream>>>(
      attn, Wob, Wob, out, NROWS, DIMM, DIMM, DIMM);
}

// Round 7
// 304.720 us; speedup vs baseline: 3.2959x; 1.0748x over previous
//
#include <hip/hip_runtime.h>
#include <hip/hip_bf16.h>

typedef __hip_bfloat16 bf16;
typedef __attribute__((ext_vector_type(4))) float f32x4;
typedef __attribute__((ext_vector_type(16))) float f32x16;
typedef __attribute__((ext_vector_type(8))) short short8;
typedef __attribute__((ext_vector_type(4))) unsigned u32x4;

#define NHEAD 16
#define NKV 4
#define HD 128
#define BATCH 4
#define SEQ 2048
#define DIMM 2048
#define NROWS (BATCH*SEQ)        // 8192
#define QKVN (DIMM + 2*NKV*HD)   // 3072

__device__ inline void gload_lds16(const bf16* g, bf16* l) {
  __builtin_amdgcn_global_load_lds(
      (const __attribute__((address_space(1))) unsigned int*)g,
      (__attribute__((address_space(3))) unsigned int*)l, 16, 0, 0);
}

__device__ inline unsigned cvtpk(float a, float b) {
  unsigned r;
  asm("v_cvt_pk_bf16_f32 %0, %1, %2" : "=v"(r) : "v"(a), "v"(b));
  return r;
}
__device__ inline void pswap(unsigned& x, unsigned& y) {
  asm volatile("v_permlane32_swap_b32 %0, %1" : "+v"(x), "+v"(y));
}
__device__ inline float bf2f(short s) {
  return __uint_as_float(((unsigned)(unsigned short)s) << 16);
}
__device__ inline short f2bfbits(float f) {
  bf16 h = __float2bfloat16(f);
  return *reinterpret_cast<short*>(&h);
}

// ---------------- fused fp32 -> bf16 conversion (all 4 tensors) ----------------
#define CVTN0 ((size_t)NROWS * DIMM)      // x      16.78M
#define CVTN1 ((size_t)DIMM * DIMM)       // Wq      4.19M
#define CVTN2 ((size_t)2 * NKV * HD * DIMM) // Wkv   2.10M
#define CVTN3 ((size_t)DIMM * DIMM)       // Wo      4.19M
__global__ void cvt_all(const float* __restrict__ x, const float* __restrict__ wq,
                        const float* __restrict__ wkv, const float* __restrict__ wo,
                        bf16* __restrict__ xb, bf16* __restrict__ wqb,
                        bf16* __restrict__ wkvb, bf16* __restrict__ wob) {
  const size_t total = CVTN0 + CVTN1 + CVTN2 + CVTN3;
  for (size_t i = ((size_t)blockIdx.x * blockDim.x + threadIdx.x) * 4; i < total;
       i += (size_t)gridDim.x * blockDim.x * 4) {
    const float* s;
    bf16* d;
    size_t off;
    if (i < CVTN0) { s = x; d = xb; off = i; }
    else if (i < CVTN0 + CVTN1) { s = wq; d = wqb; off = i - CVTN0; }
    else if (i < CVTN0 + CVTN1 + CVTN2) { s = wkv; d = wkvb; off = i - CVTN0 - CVTN1; }
    else { s = wo; d = wob; off = i - CVTN0 - CVTN1 - CVTN2; }
    const float4 v = *reinterpret_cast<const float4*>(s + off);
    alignas(8) bf16 t[4] = {__float2bfloat16(v.x), __float2bfloat16(v.y),
                            __float2bfloat16(v.z), __float2bfloat16(v.w)};
    *reinterpret_cast<uint2*>(d + off) = *reinterpret_cast<const uint2*>(t);
  }
}

__device__ inline void store_c(float* p, float v) { *p = v; }
__device__ inline void store_c(bf16* p, float v) { *p = __float2bfloat16(v); }

// ---------------- GEMM 256x256 tile, BK=64, 8 waves, pipelined ----------------
// st_16x32 swizzle (m201-exact): chunk c of row ^= ((row>>3)&1)<<1, both sides.
// Per sub-phase: vmcnt(8)+barrier+sched_barrier, 12 ds_read_b128 (compiler-
// scheduled counted lgkmcnt vs MFMA), stage next group (4 gload_lds), 32 MFMA
// under setprio.
template <typename OutT>
__global__ __launch_bounds__(512, 2) void gemm256(
    const bf16* __restrict__ A, const bf16* __restrict__ B0,
    const bf16* __restrict__ B1, OutT* __restrict__ C,
    int M, int N, int K, int Nsplit) {
  __shared__ __align__(16) short As[2][2][256 * 32];
  __shared__ __align__(16) short Bs[2][2][256 * 32];
  const int tid = threadIdx.x;
  const int w = tid >> 6, l = tid & 63;
  const int m0 = blockIdx.x * 256, n0 = blockIdx.y * 256;
  const bf16* Ap = A + (size_t)m0 * K;
  const bf16* Bp = (n0 < Nsplit) ? (B0 + (size_t)n0 * K)
                                 : (B1 + (size_t)(n0 - Nsplit) * K);
  const int wr = w >> 2, wc = w & 3;  // wave grid 2(M) x 4(N)
  const int lr = l & 15, lc = l >> 4;
  const int swz = lc ^ (((lr >> 3) & 1) << 1);  // st_16x32 read swizzle

  f32x4 acc[8][4] = {};
  const int KT = K >> 6;

  auto stage = [&](int kt, int kh, int buf) {
#pragma unroll
    for (int j = 0; j < 2; ++j) {
      const int cbase = j * 512 + w * 64;  // wave-uniform chunk base
      const int ch = cbase + l;
      const int row = ch >> 2, c = ch & 3;
      const int sc = c ^ (((row >> 3) & 1) << 1);  // st_16x32 source pre-swizzle
      const int gcol = kt * 64 + kh * 32 + sc * 8;
      gload_lds16(Ap + (size_t)row * K + gcol, (bf16*)&As[buf][kh][cbase * 8]);
      gload_lds16(Bp + (size_t)row * K + gcol, (bf16*)&Bs[buf][kh][cbase * 8]);
    }
  };

  stage(0, 0, 0);
  stage(0, 1, 0);
  stage(1, 0, 1);

  for (int kt = 0; kt < KT; ++kt) {
    const int cur = kt & 1;
#pragma unroll
    for (int kh = 0; kh < 2; ++kh) {
      if (kt < KT - 1) {
        asm volatile("s_waitcnt vmcnt(8)" ::: "memory");
      } else if (kh == 0) {
        asm volatile("s_waitcnt vmcnt(4)" ::: "memory");
      } else {
        asm volatile("s_waitcnt vmcnt(0)" ::: "memory");
      }
      __builtin_amdgcn_s_barrier();
      __builtin_amdgcn_sched_barrier(0);

      short8 a[8], b[4];
      const short* Ab = &As[cur][kh][0];
      const short* Bb = &Bs[cur][kh][0];
#pragma unroll
      for (int mr = 0; mr < 8; ++mr)
        a[mr] = *(const short8*)&Ab[(wr * 128 + mr * 16 + lr) * 32 + swz * 8];
#pragma unroll
      for (int nr = 0; nr < 4; ++nr)
        b[nr] = *(const short8*)&Bb[(wc * 64 + nr * 16 + lr) * 32 + swz * 8];

      {
        const int g = 2 * kt + kh + 3;
        const int st = g >> 1;
        if (st < KT) stage(st, g & 1, st & 1);
      }

      __builtin_amdgcn_s_setprio(1);
#pragma unroll
      for (int mr = 0; mr < 8; ++mr)
#pragma unroll
        for (int nr = 0; nr < 4; ++nr)
          acc[mr][nr] = __builtin_amdgcn_mfma_f32_16x16x32_bf16(
              a[mr], b[nr], acc[mr][nr], 0, 0, 0);
      __builtin_amdgcn_s_setprio(0);
    }
  }

  const int cr4 = (l >> 4) * 4;
#pragma unroll
  for (int mr = 0; mr < 8; ++mr)
#pragma unroll
    for (int nr = 0; nr < 4; ++nr)
#pragma unroll
      for (int r = 0; r < 4; ++r) {
        const int row = m0 + wr * 128 + mr * 16 + cr4 + r;
        const int col = n0 + wc * 64 + nr * 16 + lr;
        store_c(&C[(size_t)row * N + col], acc[mr][nr][r]);
      }
}

// ---------------- RoPE, vectorized (8 d-pairs / thread) ----------------
// q heads get prescale = 1/sqrt(128)*log2(e)
__global__ void rope_kernel(bf16* __restrict__ qkv) {
  const int idx = blockIdx.x * blockDim.x + threadIdx.x;  // NROWS*20*8 threads
  const int dc = idx & 7;
  const int slot = (idx >> 3) % 20;
  const int row = idx / (8 * 20);
  const int col = (slot < 16) ? slot * 128 : DIMM + (slot - 16) * 128;
  const size_t base = (size_t)row * QKVN + col;
  const int pos = row & (SEQ - 1);
  const float psc = (slot < 16) ? 0.12751879895f : 1.0f;
  short8 lo = *(const short8*)(qkv + base + dc * 8);
  short8 hi = *(const short8*)(qkv + base + 64 + dc * 8);
  short8 olo, ohi;
#pragma unroll
  for (int j = 0; j < 8; ++j) {
    const int d = dc * 8 + j;
    const float inv = exp2f((float)d * (-2.0f / 128.0f) * 13.287712379549449f);
    float sn, cs;
    __sincosf((float)pos * inv, &sn, &cs);
    const float flo = bf2f(lo[j]), fhi = bf2f(hi[j]);
    olo[j] = f2bfbits((flo * cs - fhi * sn) * psc);
    ohi[j] = f2bfbits((fhi * cs + flo * sn) * psc);
  }
  *(short8*)(qkv + base + dc * 8) = olo;
  *(short8*)(qkv + base + 64 + dc * 8) = ohi;
}

// ---------------- V transpose: qkv V-part -> vtg[kvh][d][b*SEQ+s] ----------------
__global__ __launch_bounds__(256) void vtrans_kernel(const bf16* __restrict__ qkv,
                                                     bf16* __restrict__ vtg) {
  __shared__ short T[64 * 72];
  const int si = blockIdx.x * 64;
  const int di = blockIdx.y * 64;
  const int b = blockIdx.z >> 2, kvh = blockIdx.z & 3;
  const int t = threadIdx.x;
  const int r = t >> 2, c2 = (t & 3) * 2;
  const bf16* src =
      qkv + (size_t)(b * SEQ + si + r) * QKVN + DIMM + NKV * HD + kvh * 128 + di;
#pragma unroll
  for (int i = 0; i < 2; ++i)
    *(short8*)&T[r * 72 + (c2 + i) * 8] = *(const short8*)(src + (c2 + i) * 8);
  __syncthreads();
#pragma unroll
  for (int i = 0; i < 2; ++i) {
    short8 v;
    const int s8 = (c2 + i) * 8;
#pragma unroll
    for (int j = 0; j < 8; ++j) v[j] = T[(s8 + j) * 72 + r];
    *(short8*)(vtg + (size_t)(kvh * 128 + di + r) * NROWS + b * SEQ + si + s8) = v;
  }
}

// ---------------- Flash attention: 8 waves x 32 q-rows, KVBLK=64, swapped QK^T ----
__global__ __launch_bounds__(512, 2) void attn_kernel(
    const bf16* __restrict__ qkv, const bf16* __restrict__ vtg,
    bf16* __restrict__ aout) {
  __shared__ __align__(16) short KsL[2][64 * 128];
  __shared__ __align__(16) short VtL[2][128 * 64];
  const int tid = threadIdx.x, w = tid >> 6, l = tid & 63;
  const int lq = l & 31, hi = l >> 5;
  const int id = blockIdx.x;
  const int half = id >> 8, rr = id & 255;
  const int bh = (rr >> 3) + half * 32;
  const int j = rr & 7;
  const int qb = half ? j : 7 - j;
  const int b = bh >> 4, h = bh & 15, kvh = h >> 2;
  const int qw0 = qb * 256 + w * 32;
  const int qg = qw0 + lq;

  short8 qf[8];
  {
    const bf16* qptr = qkv + (size_t)(b * SEQ + qg) * QKVN + h * 128 + hi * 8;
#pragma unroll
    for (int s = 0; s < 8; ++s) qf[s] = *(const short8*)(qptr + s * 16);
  }

  f32x16 o[4] = {};
  float m = -1e30f, lsum = 0.f;
  const int ntiles = qb * 4 + 4;

  const bf16* Kgb = qkv + (size_t)(b * SEQ) * QKVN + DIMM + kvh * 128;
  const bf16* Vgb = vtg + (size_t)kvh * 128 * NROWS + b * SEQ;

  auto stage = [&](int kt, int buf) {
#pragma unroll
    for (int rd = 0; rd < 2; ++rd) {
      const int cb = (w * 2 + rd) * 64;
      {
        const int lc = cb + l, k = lc >> 4, c = lc & 15;
        gload_lds16(Kgb + (size_t)(kt * 64 + k) * QKVN + ((c ^ (k & 7)) * 8),
                    (bf16*)&KsL[buf][cb * 8]);
      }
      {
        const int lc = cb + l, d = lc >> 3, c = lc & 7;
        gload_lds16(Vgb + (size_t)d * NROWS + kt * 64 + ((c ^ (d & 7)) * 8),
                    (bf16*)&VtL[buf][cb * 8]);
      }
    }
  };

  stage(0, 0);
  asm volatile("s_waitcnt vmcnt(0)" ::: "memory");
  __builtin_amdgcn_s_barrier();
  __builtin_amdgcn_sched_barrier(0);

  for (int kt = 0; kt < ntiles; ++kt) {
    const int cur = kt & 1;
    if (kt + 1 < ntiles) stage(kt + 1, cur ^ 1);

    if (kt * 64 <= qw0 + 31) {
      f32x16 st[2];
#pragma unroll
      for (int ks = 0; ks < 2; ++ks) {
        const short* kb = &KsL[cur][(ks * 32 + lq) * 128];
        const int r7 = lq & 7;
        f32x16 acc = {};
#pragma unroll
        for (int s = 0; s < 8; ++s) {
          const short8 kf = *(const short8*)&kb[((2 * s + hi) ^ r7) * 8];
          acc = __builtin_amdgcn_mfma_f32_32x32x16_bf16(kf, qf[s], acc, 0, 0, 0);
        }
        st[ks] = acc;
      }
      if (kt * 64 + 63 > qw0) {
#pragma unroll
        for (int ks = 0; ks < 2; ++ks)
#pragma unroll
          for (int r = 0; r < 16; ++r) {
            const int kg = kt * 64 + ks * 32 + (r & 3) + 8 * (r >> 2) + 4 * hi;
            if (kg > qg) st[ks][r] = -1e30f;
          }
      }
      float t[16];
#pragma unroll
      for (int r = 0; r < 16; ++r) t[r] = fmaxf(st[0][r], st[1][r]);
#pragma unroll
      for (int d2 = 8; d2 > 0; d2 >>= 1)
#pragma unroll
        for (int r = 0; r < 8; ++r)
          if (r < d2) t[r] = fmaxf(t[r], t[r + d2]);
      float pm = fmaxf(t[0], __shfl_xor(t[0], 32));
      if (!__all(pm <= m + 11.0f)) {
        const float mnew = fmaxf(m, pm);
        const float fsc = __builtin_amdgcn_exp2f(m - mnew);
        m = mnew;
        lsum *= fsc;
#pragma unroll
        for (int r = 0; r < 16; ++r) {
          const float fq = __shfl(fsc, (r & 3) + 8 * (r >> 2) + 4 * hi);
#pragma unroll
          for (int db = 0; db < 4; ++db) o[db][r] *= fq;
        }
      }
      short8 pa[4];
#pragma unroll
      for (int ks = 0; ks < 2; ++ks) {
        float p[16];
        float s0 = 0.f, s1 = 0.f, s2 = 0.f, s3 = 0.f;
#pragma unroll
        for (int r = 0; r < 16; r += 4) {
          p[r] = __builtin_amdgcn_exp2f(st[ks][r] - m);         s0 += p[r];
          p[r + 1] = __builtin_amdgcn_exp2f(st[ks][r + 1] - m); s1 += p[r + 1];
          p[r + 2] = __builtin_amdgcn_exp2f(st[ks][r + 2] - m); s2 += p[r + 2];
          p[r + 3] = __builtin_amdgcn_exp2f(st[ks][r + 3] - m); s3 += p[r + 3];
        }
        lsum += (s0 + s1) + (s2 + s3);
#pragma unroll
        for (int hf = 0; hf < 2; ++hf) {
          unsigned x0 = cvtpk(p[hf * 8 + 0], p[hf * 8 + 1]);
          unsigned y0 = cvtpk(p[hf * 8 + 4], p[hf * 8 + 5]);
          unsigned x1 = cvtpk(p[hf * 8 + 2], p[hf * 8 + 3]);
          unsigned y1 = cvtpk(p[hf * 8 + 6], p[hf * 8 + 7]);
          pswap(x0, y0);
          pswap(x1, y1);
          union { u32x4 u; short8 s; } pk;
          pk.u = u32x4{x0, x1, y0, y1};
          pa[ks * 2 + hf] = pk.s;
        }
      }
#pragma unroll
      for (int s = 0; s < 4; ++s) {
        const int cc = ((2 * s + hi) ^ (lq & 7)) * 8;
#pragma unroll
        for (int db = 0; db < 4; ++db) {
          const short8 vb = *(const short8*)&VtL[cur][(db * 32 + lq) * 64 + cc];
          o[db] = __builtin_amdgcn_mfma_f32_32x32x16_bf16(pa[s], vb, o[db], 0, 0, 0);
        }
      }
    }

    asm volatile("s_waitcnt vmcnt(0)" ::: "memory");
    __builtin_amdgcn_s_barrier();
    __builtin_amdgcn_sched_barrier(0);
  }

  const float lf = lsum + __shfl_xor(lsum, 32);
#pragma unroll
  for (int r = 0; r < 16; ++r) {
    const int qr = (r & 3) + 8 * (r >> 2) + 4 * hi;
    const float linv = 1.0f / __shfl(lf, qr);
    bf16* op = aout + (size_t)(b * SEQ + qw0 + qr) * DIMM + h * 128 + lq;
#pragma unroll
    for (int db = 0; db < 4; ++db)
      op[db * 32] = __float2bfloat16(o[db][r] * linv);
  }
}

// ---------------- launcher ----------------
extern "C" void kernel_launch(void* const* d_in, const int* in_sizes, int n_in,
                              void* d_out, int out_size, void* d_ws, size_t ws_size,
                              hipStream_t stream) {
  const float* x = (const float*)d_in[0];
  const float* Wq = (const float*)d_in[1];
  const float* Wkv = (const float*)d_in[2];
  const float* Wo = (const float*)d_in[3];
  float* out = (float*)d_out;

  bf16* xb = (bf16*)d_ws;                          // 8192*2048
  bf16* Wqb = xb + (size_t)NROWS * DIMM;           // 2048*2048
  bf16* Wkvb = Wqb + (size_t)DIMM * DIMM;          // 1024*2048
  bf16* Wob = Wkvb + (size_t)2 * NKV * HD * DIMM;  // 2048*2048
  bf16* attn = Wob + (size_t)DIMM * DIMM;          // 8192*2048
  bf16* qkv = (bf16*)d_out;                        // 50.3MB scratch in d_out
  bf16* vtg = (bf16*)d_out + (size_t)NROWS * QKVN; // 8MB more, still in d_out

  cvt_all<<<2048, 256, 0, stream>>>(x, Wq, Wkv, Wo, xb, Wqb, Wkvb, Wob);

  gemm256<bf16><<<dim3(NROWS / 256, QKVN / 256), 512, 0, stream>>>(
      xb, Wqb, Wkvb, qkv, NROWS, QKVN, DIMM, DIMM);

  rope_kernel<<<(NROWS * 20 * 8) / 256, 256, 0, stream>>>(qkv);

  vtrans_kernel<<<dim3(SEQ / 64, 2, 16), 256, 0, stream>>>(qkv, vtg);

  attn_kernel<<<dim3(512), 512, 0, stream>>>(qkv, vtg, attn);

  gemm256<float><<<dim3(NROWS / 256, DIMM / 256), 512, 0, stream>>>(
      attn, Wob, Wob, out, NROWS, DIMM, DIMM, DIMM);
}